// Round 16
// baseline (2780.368 us; speedup 1.0000x reference)
//
#include <hip/hip_runtime.h>
#include <hip/hip_bf16.h>

typedef __attribute__((ext_vector_type(8))) short bf16x8;
typedef __attribute__((ext_vector_type(4))) float f32x4;
typedef __attribute__((ext_vector_type(4))) unsigned int u32x4;
typedef __attribute__((ext_vector_type(2))) unsigned int u32x2;
typedef unsigned short u16;
typedef unsigned int u32;

#define SENT 0x7FC07FC0u   // 2x bf16 NaN — unreachable as real h data

__device__ __forceinline__ u16 f2bf(float f) {
  union { float f; unsigned u; } v; v.f = f;
  unsigned r = v.u + 0x7FFFu + ((v.u >> 16) & 1u);   // RTNE
  return (u16)(r >> 16);
}

__device__ __forceinline__ float sigm_fast(float x) {
  return __builtin_amdgcn_rcpf(1.f + __expf(-x));
}
__device__ __forceinline__ float tanh_fast(float x) {
  x = fminf(fmaxf(x, -15.f), 15.f);
  float e = __expf(2.f * x);
  return (e - 1.f) * __builtin_amdgcn_rcpf(e + 1.f);
}

// ---- untracked (inline-asm) memory ops: caller owns the vmcnt ledger ----
__device__ __forceinline__ void ld_llc_b128(const u16* p, bf16x8& r) {  // coherent
  asm volatile("global_load_dwordx4 %0, %1, off sc0 sc1" : "=&v"(r) : "v"(p));
}
__device__ __forceinline__ void ld_g_b128(const u16* p, bf16x8& r) {    // cached
  asm volatile("global_load_dwordx4 %0, %1, off" : "=&v"(r) : "v"(p));
}
__device__ __forceinline__ void st_llc_b64(u16* p, u32x2 v) {           // coherent
  asm volatile("global_store_dwordx2 %0, %1, off sc0 sc1" :: "v"(p), "v"(v) : "memory");
}
__device__ __forceinline__ void st_g_b32(u32* p, u32 v) {               // cached
  asm volatile("global_store_dword %0, %1, off" :: "v"(p), "v"(v) : "memory");
}

// ---------------------------------------------------------------------------
// fold (all 4 gates, z = gate): Wt[(j*4+g)][k] = sum_m P[m][j]*(W[k][m]*cos(rx[m]))
// ---------------------------------------------------------------------------
__global__ __launch_bounds__(256) void fold_kernel(
    const float* __restrict__ W0, const float* __restrict__ rx0, const float* __restrict__ P0,
    const float* __restrict__ W1, const float* __restrict__ rx1, const float* __restrict__ P1,
    const float* __restrict__ W2, const float* __restrict__ rx2, const float* __restrict__ P2,
    const float* __restrict__ W3, const float* __restrict__ rx3, const float* __restrict__ P3,
    u16* __restrict__ Wt)
{
  const int g = blockIdx.z;
  const float* W  = (g == 0) ? W0  : (g == 1) ? W1  : (g == 2) ? W2  : W3;
  const float* rx = (g == 0) ? rx0 : (g == 1) ? rx1 : (g == 2) ? rx2 : rx3;
  const float* P  = (g == 0) ? P0  : (g == 1) ? P1  : (g == 2) ? P2  : P3;
  __shared__ __align__(16) float As[16][68];
  __shared__ __align__(16) float Bs[16][68];
  const int bk = blockIdx.x, bj = blockIdx.y;
  const int tid = threadIdx.x;
  const int tx = tid & 15, ty = tid >> 4;
  const int j0 = bj * 64, k0 = bk * 64;
  float acc[4][4] = {};
  for (int m0 = 0; m0 < 512; m0 += 16) {
#pragma unroll
    for (int l = 0; l < 4; ++l) {
      int lin = tid + 256 * l;
      int mm = lin >> 6, jr = lin & 63;
      As[mm][jr] = P[(m0 + mm) * 512 + j0 + jr];
      int kk = lin >> 4, mb = lin & 15;
      Bs[mb][kk] = W[(k0 + kk) * 512 + m0 + mb] * cosf(rx[m0 + mb]);
    }
    __syncthreads();
#pragma unroll
    for (int mm = 0; mm < 16; ++mm) {
      f32x4 a = *(const f32x4*)&As[mm][ty * 4];
      f32x4 b = *(const f32x4*)&Bs[mm][tx * 4];
#pragma unroll
      for (int i = 0; i < 4; ++i)
#pragma unroll
        for (int jj = 0; jj < 4; ++jj)
          acc[i][jj] += a[i] * b[jj];
    }
    __syncthreads();
  }
#pragma unroll
  for (int i = 0; i < 4; ++i) {
    int j = j0 + ty * 4 + i;
    size_t n = (size_t)(j * 4 + g);
    ushort4 w;
    w.x = f2bf(acc[i][0]); w.y = f2bf(acc[i][1]);
    w.z = f2bf(acc[i][2]); w.w = f2bf(acc[i][3]);
    *(ushort4*)(Wt + n * 1024 + k0 + tx * 4) = w;
  }
}

// bpn[j*4+g]; grid 32 = 4 gates x 8 j-blocks
__global__ __launch_bounds__(256) void fold_bias(
    const float* __restrict__ b0, const float* __restrict__ rx0, const float* __restrict__ P0,
    const float* __restrict__ b1, const float* __restrict__ rx1, const float* __restrict__ P1,
    const float* __restrict__ b2, const float* __restrict__ rx2, const float* __restrict__ P2,
    const float* __restrict__ b3, const float* __restrict__ rx3, const float* __restrict__ P3,
    float* __restrict__ bpn)
{
  const int g = blockIdx.x >> 3, jb = blockIdx.x & 7;
  const float* b  = (g == 0) ? b0  : (g == 1) ? b1  : (g == 2) ? b2  : b3;
  const float* rx = (g == 0) ? rx0 : (g == 1) ? rx1 : (g == 2) ? rx2 : rx3;
  const float* P  = (g == 0) ? P0  : (g == 1) ? P1  : (g == 2) ? P2  : P3;
  __shared__ float bc[512];
  __shared__ float red[4][65];
  const int tid = threadIdx.x;
  bc[tid] = b[tid] * cosf(rx[tid]);
  bc[tid + 256] = b[tid + 256] * cosf(rx[tid + 256]);
  __syncthreads();
  const int jl = tid & 63, msub = tid >> 6;
  const int j = jb * 64 + jl;
  float acc = 0.f;
  for (int m = msub * 128; m < msub * 128 + 128; ++m)
    acc += bc[m] * P[m * 512 + j];
  red[msub][jl] = acc;
  __syncthreads();
  if (msub == 0)
    bpn[j * 4 + g] = red[0][jl] + red[1][jl] + red[2][jl] + red[3][jl];
}

__global__ __launch_bounds__(256) void xcvt_kernel(
    const float* __restrict__ x, u16* __restrict__ xb)
{
  size_t i = (size_t)blockIdx.x * 256 + threadIdx.x;
  f32x4 v = *(const f32x4*)(x + i * 4);
  ushort4 w;
  w.x = f2bf(v[0]); w.y = f2bf(v[1]); w.z = f2bf(v[2]); w.w = f2bf(v[3]);
  *(ushort4*)(xb + i * 4) = w;
}

// sentinel-fill hseq (256 slabs = 8,388,608 dwords), 4 dwords per thread
__global__ __launch_bounds__(256) void init_hseq(u32* hseq32) {
  size_t i = ((size_t)blockIdx.x * 256 + threadIdx.x) * 4;
  u32x4 s = {SENT, SENT, SENT, SENT};
  *(u32x4*)(hseq32 + i) = s;
}

// zero hz (fallback h) + cbuf, every launch (replay determinism)
__global__ __launch_bounds__(256) void init_small(u32* hz32, float* cbuf) {
  int i = blockIdx.x * 256 + threadIdx.x;      // 65536
  hz32[i] = 0;
  cbuf[i] = 0.f;
}

__global__ __launch_bounds__(256) void tail_kernel(
    const float* __restrict__ hlast, const float* __restrict__ c,
    float* __restrict__ hx, float* __restrict__ cx)
{
  int i = blockIdx.x * 256 + threadIdx.x;
  hx[i] = hlast[i];
  cx[i] = c[i];
}

// ---------------------------------------------------------------------------
// fallback single-step kernel (R1-proven)
// ---------------------------------------------------------------------------
__global__ __launch_bounds__(256) void step_kernel(
    const u16* __restrict__ xb_t, const u16* __restrict__ h_in,
    u16* __restrict__ h_out, const u16* __restrict__ Wt,
    const float* __restrict__ bpn, float* __restrict__ cbuf,
    float* __restrict__ out_t)
{
  __shared__ float pre_s[32][33];
  const int bid = blockIdx.x;
  const int mb = bid >> 6, nb = bid & 63;
  const int b0 = mb * 32, n0 = nb * 32;
  const int tid = threadIdx.x;
  const int wv = tid >> 6, lane = tid & 63;
  const int rt = wv >> 1, nt = wv & 1;
  const int l15 = lane & 15, kg = lane >> 4;
  const int brow = b0 + rt * 16 + l15;
  const int ncol = n0 + nt * 16 + l15;
  const u16* wrow = Wt + (size_t)ncol * 1024;
  const u16* xrow = xb_t + (size_t)brow * 512;
  const u16* hrow = h_in + (size_t)brow * 512;
  f32x4 acc = {0.f, 0.f, 0.f, 0.f};
#pragma unroll 8
  for (int kk = 0; kk < 32; ++kk) {
    const int kb = kk * 32 + kg * 8;
    bf16x8 bfrag = *(const bf16x8*)(wrow + kb);
    bf16x8 afrag;
    if (kb < 512) afrag = *(const bf16x8*)(xrow + kb);
    else          afrag = *(const bf16x8*)(hrow + (kb - 512));
    acc = __builtin_amdgcn_mfma_f32_16x16x32_bf16(afrag, bfrag, acc, 0, 0, 0);
  }
  const float bias = bpn[ncol];
#pragma unroll
  for (int q = 0; q < 4; ++q)
    pre_s[rt * 16 + kg * 4 + q][nt * 16 + l15] = acc[q] + bias;
  __syncthreads();
  const int bb = tid >> 3, jo = tid & 7;
  float pf = pre_s[bb][jo * 4 + 0];
  float pi = pre_s[bb][jo * 4 + 1];
  float pu = pre_s[bb][jo * 4 + 2];
  float po = pre_s[bb][jo * 4 + 3];
  float fg = 1.f / (1.f + __expf(-pf));
  float ig = 1.f / (1.f + __expf(-pi));
  float gg = tanhf(pu);
  float og = 1.f / (1.f + __expf(-po));
  size_t idx = (size_t)(b0 + bb) * 512 + (size_t)(nb * 8 + jo);
  float cv = fg * cbuf[idx] + ig * gg;
  cbuf[idx] = cv;
  float hv = og * tanhf(cv);
  out_t[idx] = hv;
  h_out[idx] = f2bf(hv);
}

// ---------------------------------------------------------------------------
// persistent recurrence v10: FRESH-SLAB sentinels, zero barriers, zero drains.
// hseq[256][128][512] bf16: slab t holds h produced at step t (consumed at
// t+1). Every address written exactly once -> no resets, no staleness hazard
// (memory is monotonic: sentinel or final value). Each wave's 16-col tile =
// 4 complete h-cols x 4 gates (n-interleaved Wt) -> gate transpose + cell
// update are intra-wave (own LDS patch, lgkmcnt only). Producer fires one
// packed 8B h-store per row and moves on; consumer's load IS the poll, with
// selective sc0sc1 retry. Ledger: [h-st, out, x16] -> vmcnt(16) proves x.
// ---------------------------------------------------------------------------
__global__ __launch_bounds__(256, 1) void qlstm_persistent(
    const u16* __restrict__ Xbf,    // [256][128][512] bf16
    u16* __restrict__ hseq,         // [256][128][512] bf16, sentinel-filled
    const u16* __restrict__ Wt,     // [2048][1024] bf16, n = j*4+g
    const float* __restrict__ bpn,  // [2048] f32
    float* __restrict__ out)        // [256][128][512] + hx + cx
{
  __shared__ float pre_s[4][16][17];
  const int bid = blockIdx.x;
  const int mb = bid & 3, nb = bid >> 2;     // group spread across XCDs
  const int b0 = mb * 32, n0 = nb * 32;
  const int tid = threadIdx.x;
  const int wv = tid >> 6, lane = tid & 63;
  const int rt = wv >> 1, nt = wv & 1;
  const int l15 = lane & 15, kg = lane >> 4;
  const int brow = b0 + rt * 16 + l15;
  const int ncol = n0 + nt * 16 + l15;

  // both W halves register-resident / compiler-managed
  const u16* wrow = Wt + (size_t)ncol * 1024;
  bf16x8 warr[32];
#pragma unroll
  for (int kk = 0; kk < 32; ++kk)
    warr[kk] = *(const bf16x8*)(wrow + kk * 32 + kg * 8);
  const float bnc = bpn[ncol];

  // intra-wave cell mapping: lane -> (row = l15, local h-col = kg)
  const int jglob = nb * 8 + nt * 4 + kg;            // this lane's h column
  const size_t eidx = (size_t)brow * 512 + (size_t)jglob;
  const size_t hrow_off = (size_t)brow * 512 + (size_t)(nb * 8 + nt * 4);
  float cst = 0.f, hl = 0.f;

  // prologue: x-loads for t=0, drained once
  bf16x8 xf[16];
  {
    const u16* xr = Xbf + (size_t)brow * 512;
#pragma unroll
    for (int kk = 0; kk < 16; ++kk)
      ld_g_b128(xr + kk * 32 + kg * 8, xf[kk]);
    asm volatile("s_waitcnt vmcnt(0)" ::: "memory");
  }

  for (int t = 0; t < 256; ++t) {
    // ---- issue coherent h-loads from slab t-1 (the load IS the poll) ----
    bf16x8 hf[16];
    const u16* hr = hseq + (size_t)(t - 1) * 65536 + (size_t)brow * 512;
    if (t > 0) {
#pragma unroll
      for (int kk = 0; kk < 16; ++kk)
        ld_llc_b128(hr + kk * 32 + kg * 8, hf[kk]);
    }
    // x landed: 18 older ops [h-st, out, x16] drained, keep the 16 h-loads
    asm volatile("s_waitcnt vmcnt(16)" ::: "memory");
    __builtin_amdgcn_sched_barrier(0);

    // x-MFMAs from registers (overlap h-load flight)
    f32x4 ax0 = {0,0,0,0}, ax1 = {0,0,0,0};
#pragma unroll
    for (int kk = 0; kk < 16; kk += 2) {
      ax0 = __builtin_amdgcn_mfma_f32_16x16x32_bf16(xf[kk],     warr[kk],     ax0, 0, 0, 0);
      ax1 = __builtin_amdgcn_mfma_f32_16x16x32_bf16(xf[kk + 1], warr[kk + 1], ax1, 0, 0, 0);
    }

    // detect + selective retry
    f32x4 ah0 = {0,0,0,0}, ah1 = {0,0,0,0};
    if (t > 0) {
      asm volatile("s_waitcnt vmcnt(0)" ::: "memory");
      __builtin_amdgcn_sched_barrier(0);
      int guard = 0;
      for (;;) {
        u32 stale = 0;
#pragma unroll
        for (int kk = 0; kk < 16; ++kk) {
          union { bf16x8 v; u32 d[4]; } u; u.v = hf[kk];
          u32 s = (u32)((u.d[0] == SENT) | (u.d[1] == SENT) |
                        (u.d[2] == SENT) | (u.d[3] == SENT));
          stale |= s << kk;
        }
        if (__all((int)(stale == 0))) break;
        if (++guard > 3000) break;             // bounded: fail loudly, no hang
        __builtin_amdgcn_s_sleep(1);
#pragma unroll
        for (int kk = 0; kk < 16; ++kk)
          if ((stale >> kk) & 1)
            ld_llc_b128(hr + kk * 32 + kg * 8, hf[kk]);
        asm volatile("s_waitcnt vmcnt(0)" ::: "memory");
        __builtin_amdgcn_sched_barrier(0);
      }
      __builtin_amdgcn_sched_barrier(0);
#pragma unroll
      for (int kk = 0; kk < 16; kk += 2) {
        ah0 = __builtin_amdgcn_mfma_f32_16x16x32_bf16(hf[kk],     warr[16 + kk],     ah0, 0, 0, 0);
        ah1 = __builtin_amdgcn_mfma_f32_16x16x32_bf16(hf[kk + 1], warr[16 + kk + 1], ah1, 0, 0, 0);
      }
    }
    f32x4 acc = (ax0 + ax1) + (ah0 + ah1);

    // intra-wave gate transpose (own LDS patch, lgkmcnt only, NO barrier)
    // C/D layout: col = l15, row = kg*4+q
#pragma unroll
    for (int q = 0; q < 4; ++q)
      pre_s[wv][kg * 4 + q][l15] = acc[q] + bnc;
    asm volatile("s_waitcnt lgkmcnt(0)" ::: "memory");
    __builtin_amdgcn_sched_barrier(0);
    f32x4 g4 = *(const f32x4*)&pre_s[wv][l15][kg * 4];
    asm volatile("s_waitcnt lgkmcnt(0)" ::: "memory");
    __builtin_amdgcn_sched_barrier(0);

    // gates + cell update: lane owns (row = brow, col = jglob)
    cst = sigm_fast(g4[0]) * cst + sigm_fast(g4[1]) * tanh_fast(g4[2]);
    float hv = sigm_fast(g4[3]) * tanh_fast(cst);
    hl = hv;

    // fire-and-forget packed h-store: 4 cols of this row -> one dwordx2
    u16 myh = f2bf(hv);
    u32 w  = (u32)myh | ((u32)(u16)__shfl_xor((int)(u32)myh, 16) << 16);
    u32 w2 = (u32)__shfl_xor((int)w, 32);
    if (kg == 0) {
      u32x2 hw = {w, w2};
      st_llc_b64(hseq + (size_t)t * 65536 + hrow_off, hw);
    }

    // out store + x prefetch for t+1 (fire-and-forget, fly across the step)
    union { float f; u32 u; } ho; ho.f = hv;
    st_g_b32((u32*)(out + (size_t)t * 65536 + eidx), ho.u);
    if (t < 255) {
      const u16* xr = Xbf + (size_t)(t + 1) * 65536 + (size_t)brow * 512;
#pragma unroll
      for (int kk = 0; kk < 16; ++kk)
        ld_g_b128(xr + kk * 32 + kg * 8, xf[kk]);
    }
  }

  asm volatile("s_waitcnt vmcnt(0)" ::: "memory");
  out[(size_t)256 * 65536 + eidx] = hl;
  out[(size_t)256 * 65536 + 65536 + eidx] = cst;
}

// ---------------------------------------------------------------------------
extern "C" void kernel_launch(void* const* d_in, const int* in_sizes, int n_in,
                              void* d_out, int out_size, void* d_ws, size_t ws_size,
                              hipStream_t stream) {
  (void)in_sizes; (void)n_in; (void)out_size;
  const float* inp = (const float*)d_in[0];
  float* out = (float*)d_out;

  // ws: Xbf 33554432 | Wt 4194304 | bpn 8192 | hseq 33554432 | hz 262144 | cbuf 262144
  char* base = (char*)d_ws;
  u16*   Xbf   = (u16*)base;
  u16*   Wt    = (u16*)(base + 33554432);
  float* bpn   = (float*)(base + 33554432 + 4194304);
  u16*   hseq  = (u16*)(base + 33554432 + 4194304 + 8192);
  u16*   hz    = (u16*)(base + 33554432 + 4194304 + 8192 + 33554432);
  float* cbuf  = (float*)(base + 33554432 + 4194304 + 8192 + 33554432 + 262144);
  const size_t WS_NEED = 33554432ull + 4194304 + 8192 + 33554432 + 262144 + 262144;
  const bool big_ws = (ws_size >= WS_NEED);

  const float* W[4];  const float* b[4];  const float* rx[4];  const float* P[4];
  for (int g = 0; g < 4; ++g) {
    W[g]  = (const float*)d_in[1 + 4 * g];
    b[g]  = (const float*)d_in[2 + 4 * g];
    rx[g] = (const float*)d_in[3 + 4 * g];
    P[g]  = (const float*)d_in[4 + 4 * g];
  }
  fold_kernel<<<dim3(16, 8, 4), 256, 0, stream>>>(
      W[0], rx[0], P[0], W[1], rx[1], P[1],
      W[2], rx[2], P[2], W[3], rx[3], P[3], Wt);
  fold_bias<<<dim3(32), 256, 0, stream>>>(
      b[0], rx[0], P[0], b[1], rx[1], P[1],
      b[2], rx[2], P[2], b[3], rx[3], P[3], bpn);
  xcvt_kernel<<<16384, 256, 0, stream>>>(inp, Xbf);

  bool done = false;
  if (big_ws) {
    init_hseq<<<8192, 256, 0, stream>>>((u32*)hseq);
    void* args[5];
    const u16* Xbf_c = Xbf;
    const u16* Wt_c = Wt;
    const float* bpn_c = bpn;
    u16* hseq_p = hseq;
    float* out_p = out;
    args[0] = (void*)&Xbf_c;
    args[1] = (void*)&hseq_p;
    args[2] = (void*)&Wt_c;
    args[3] = (void*)&bpn_c;
    args[4] = (void*)&out_p;
    hipError_t e = hipLaunchCooperativeKernel((const void*)qlstm_persistent,
                                              dim3(256), dim3(256), args, 0, stream);
    done = (e == hipSuccess);
  }
  if (!done) {
    // fallback: proven multi-launch path (small ws footprint: reuse hseq area
    // start for hz/cbuf if ws is small)
    u16*   hzf   = big_ws ? hz   : (u16*)(base + 33554432 + 4194304 + 8192);
    float* cbuff = big_ws ? cbuf : (float*)(base + 33554432 + 4194304 + 8192 + 262144);
    init_small<<<256, 256, 0, stream>>>((u32*)hzf, cbuff);
    for (int t = 0; t < 256; ++t) {
      const u16* xb_t  = Xbf + (size_t)t * 65536;
      const u16* h_in  = hzf + (size_t)(t & 1) * 65536;
      u16*       h_oup = hzf + (size_t)((t & 1) ^ 1) * 65536;
      float*     out_t = out + (size_t)t * 65536;
      step_kernel<<<256, 256, 0, stream>>>(xb_t, h_in, h_oup, Wt, bpn, cbuff, out_t);
    }
    tail_kernel<<<256, 256, 0, stream>>>(out + (size_t)255 * 65536, cbuff,
                                         out + (size_t)256 * 65536,
                                         out + (size_t)256 * 65536 + 65536);
  }
}

// Round 17
// 1631.280 us; speedup vs baseline: 1.7044x; 1.7044x over previous
//
#include <hip/hip_runtime.h>
#include <hip/hip_bf16.h>

typedef __attribute__((ext_vector_type(8))) short bf16x8;
typedef __attribute__((ext_vector_type(4))) float f32x4;
typedef __attribute__((ext_vector_type(2))) unsigned int u32x2;
typedef unsigned short u16;
typedef unsigned int u32;

__device__ __forceinline__ u16 f2bf(float f) {
  union { float f; unsigned u; } v; v.f = f;
  unsigned r = v.u + 0x7FFFu + ((v.u >> 16) & 1u);   // RTNE
  return (u16)(r >> 16);
}

__device__ __forceinline__ float sigm_fast(float x) {
  return __builtin_amdgcn_rcpf(1.f + __expf(-x));
}
__device__ __forceinline__ float tanh_fast(float x) {
  x = fminf(fmaxf(x, -15.f), 15.f);
  float e = __expf(2.f * x);
  return (e - 1.f) * __builtin_amdgcn_rcpf(e + 1.f);
}

// ---- untracked (inline-asm) memory ops: caller owns the vmcnt ledger ----
__device__ __forceinline__ void ld_llc_b128(const u16* p, bf16x8& r) {  // coherent
  asm volatile("global_load_dwordx4 %0, %1, off sc0 sc1" : "=&v"(r) : "v"(p));
}
__device__ __forceinline__ void ld_g_b128(const u16* p, bf16x8& r) {    // cached
  asm volatile("global_load_dwordx4 %0, %1, off" : "=&v"(r) : "v"(p));
}
__device__ __forceinline__ void st_llc_b64(u16* p, u32x2 v) {           // coherent
  asm volatile("global_store_dwordx2 %0, %1, off sc0 sc1" :: "v"(p), "v"(v) : "memory");
}
__device__ __forceinline__ void st_g_b32(u32* p, u32 v) {               // cached
  asm volatile("global_store_dword %0, %1, off" :: "v"(p), "v"(v) : "memory");
}

// ---------------------------------------------------------------------------
// fold (all 4 gates, z = gate): Wt[(j*4+g)][k] = sum_m P[m][j]*(W[k][m]*cos(rx[m]))
// ---------------------------------------------------------------------------
__global__ __launch_bounds__(256) void fold_kernel(
    const float* __restrict__ W0, const float* __restrict__ rx0, const float* __restrict__ P0,
    const float* __restrict__ W1, const float* __restrict__ rx1, const float* __restrict__ P1,
    const float* __restrict__ W2, const float* __restrict__ rx2, const float* __restrict__ P2,
    const float* __restrict__ W3, const float* __restrict__ rx3, const float* __restrict__ P3,
    u16* __restrict__ Wt)
{
  const int g = blockIdx.z;
  const float* W  = (g == 0) ? W0  : (g == 1) ? W1  : (g == 2) ? W2  : W3;
  const float* rx = (g == 0) ? rx0 : (g == 1) ? rx1 : (g == 2) ? rx2 : rx3;
  const float* P  = (g == 0) ? P0  : (g == 1) ? P1  : (g == 2) ? P2  : P3;
  __shared__ __align__(16) float As[16][68];
  __shared__ __align__(16) float Bs[16][68];
  const int bk = blockIdx.x, bj = blockIdx.y;
  const int tid = threadIdx.x;
  const int tx = tid & 15, ty = tid >> 4;
  const int j0 = bj * 64, k0 = bk * 64;
  float acc[4][4] = {};
  for (int m0 = 0; m0 < 512; m0 += 16) {
#pragma unroll
    for (int l = 0; l < 4; ++l) {
      int lin = tid + 256 * l;
      int mm = lin >> 6, jr = lin & 63;
      As[mm][jr] = P[(m0 + mm) * 512 + j0 + jr];
      int kk = lin >> 4, mb = lin & 15;
      Bs[mb][kk] = W[(k0 + kk) * 512 + m0 + mb] * cosf(rx[m0 + mb]);
    }
    __syncthreads();
#pragma unroll
    for (int mm = 0; mm < 16; ++mm) {
      f32x4 a = *(const f32x4*)&As[mm][ty * 4];
      f32x4 b = *(const f32x4*)&Bs[mm][tx * 4];
#pragma unroll
      for (int i = 0; i < 4; ++i)
#pragma unroll
        for (int jj = 0; jj < 4; ++jj)
          acc[i][jj] += a[i] * b[jj];
    }
    __syncthreads();
  }
#pragma unroll
  for (int i = 0; i < 4; ++i) {
    int j = j0 + ty * 4 + i;
    size_t n = (size_t)(j * 4 + g);
    ushort4 w;
    w.x = f2bf(acc[i][0]); w.y = f2bf(acc[i][1]);
    w.z = f2bf(acc[i][2]); w.w = f2bf(acc[i][3]);
    *(ushort4*)(Wt + n * 1024 + k0 + tx * 4) = w;
  }
}

// bpn[j*4+g]; grid 32 = 4 gates x 8 j-blocks
__global__ __launch_bounds__(256) void fold_bias(
    const float* __restrict__ b0, const float* __restrict__ rx0, const float* __restrict__ P0,
    const float* __restrict__ b1, const float* __restrict__ rx1, const float* __restrict__ P1,
    const float* __restrict__ b2, const float* __restrict__ rx2, const float* __restrict__ P2,
    const float* __restrict__ b3, const float* __restrict__ rx3, const float* __restrict__ P3,
    float* __restrict__ bpn)
{
  const int g = blockIdx.x >> 3, jb = blockIdx.x & 7;
  const float* b  = (g == 0) ? b0  : (g == 1) ? b1  : (g == 2) ? b2  : b3;
  const float* rx = (g == 0) ? rx0 : (g == 1) ? rx1 : (g == 2) ? rx2 : rx3;
  const float* P  = (g == 0) ? P0  : (g == 1) ? P1  : (g == 2) ? P2  : P3;
  __shared__ float bc[512];
  __shared__ float red[4][65];
  const int tid = threadIdx.x;
  bc[tid] = b[tid] * cosf(rx[tid]);
  bc[tid + 256] = b[tid + 256] * cosf(rx[tid + 256]);
  __syncthreads();
  const int jl = tid & 63, msub = tid >> 6;
  const int j = jb * 64 + jl;
  float acc = 0.f;
  for (int m = msub * 128; m < msub * 128 + 128; ++m)
    acc += bc[m] * P[m * 512 + j];
  red[msub][jl] = acc;
  __syncthreads();
  if (msub == 0)
    bpn[j * 4 + g] = red[0][jl] + red[1][jl] + red[2][jl] + red[3][jl];
}

__global__ __launch_bounds__(256) void xcvt_kernel(
    const float* __restrict__ x, u16* __restrict__ xb)
{
  size_t i = (size_t)blockIdx.x * 256 + threadIdx.x;
  f32x4 v = *(const f32x4*)(x + i * 4);
  ushort4 w;
  w.x = f2bf(v[0]); w.y = f2bf(v[1]); w.z = f2bf(v[2]); w.w = f2bf(v[3]);
  *(ushort4*)(xb + i * 4) = w;
}

// zero hbuf (both parities) + cbuf + flags, every launch (replay determinism)
__global__ __launch_bounds__(256) void init_kernel(u32* hbuf32, float* cbuf,
                                                   u32* flags) {
  int i = blockIdx.x * 256 + threadIdx.x;      // 65536
  hbuf32[i] = 0;
  cbuf[i] = 0.f;
  if (i < 128) flags[i] = 0;
}

__global__ __launch_bounds__(256) void tail_kernel(
    const float* __restrict__ hlast, const float* __restrict__ c,
    float* __restrict__ hx, float* __restrict__ cx)
{
  int i = blockIdx.x * 256 + threadIdx.x;
  hx[i] = hlast[i];
  cx[i] = c[i];
}

// ---------------------------------------------------------------------------
// fallback single-step kernel (R1-proven)
// ---------------------------------------------------------------------------
__global__ __launch_bounds__(256) void step_kernel(
    const u16* __restrict__ xb_t, const u16* __restrict__ h_in,
    u16* __restrict__ h_out, const u16* __restrict__ Wt,
    const float* __restrict__ bpn, float* __restrict__ cbuf,
    float* __restrict__ out_t)
{
  __shared__ float pre_s[32][33];
  const int bid = blockIdx.x;
  const int mb = bid >> 6, nb = bid & 63;
  const int b0 = mb * 32, n0 = nb * 32;
  const int tid = threadIdx.x;
  const int wv = tid >> 6, lane = tid & 63;
  const int rt = wv >> 1, nt = wv & 1;
  const int l15 = lane & 15, kg = lane >> 4;
  const int brow = b0 + rt * 16 + l15;
  const int ncol = n0 + nt * 16 + l15;
  const u16* wrow = Wt + (size_t)ncol * 1024;
  const u16* xrow = xb_t + (size_t)brow * 512;
  const u16* hrow = h_in + (size_t)brow * 512;
  f32x4 acc = {0.f, 0.f, 0.f, 0.f};
#pragma unroll 8
  for (int kk = 0; kk < 32; ++kk) {
    const int kb = kk * 32 + kg * 8;
    bf16x8 bfrag = *(const bf16x8*)(wrow + kb);
    bf16x8 afrag;
    if (kb < 512) afrag = *(const bf16x8*)(xrow + kb);
    else          afrag = *(const bf16x8*)(hrow + (kb - 512));
    acc = __builtin_amdgcn_mfma_f32_16x16x32_bf16(afrag, bfrag, acc, 0, 0, 0);
  }
  const float bias = bpn[ncol];
#pragma unroll
  for (int q = 0; q < 4; ++q)
    pre_s[rt * 16 + kg * 4 + q][nt * 16 + l15] = acc[q] + bias;
  __syncthreads();
  const int bb = tid >> 3, jo = tid & 7;
  float pf = pre_s[bb][jo * 4 + 0];
  float pi = pre_s[bb][jo * 4 + 1];
  float pu = pre_s[bb][jo * 4 + 2];
  float po = pre_s[bb][jo * 4 + 3];
  float fg = 1.f / (1.f + __expf(-pf));
  float ig = 1.f / (1.f + __expf(-pi));
  float gg = tanhf(pu);
  float og = 1.f / (1.f + __expf(-po));
  size_t idx = (size_t)(b0 + bb) * 512 + (size_t)(nb * 8 + jo);
  float cv = fg * cbuf[idx] + ig * gg;
  cbuf[idx] = cv;
  float hv = og * tanhf(cv);
  out_t[idx] = hv;
  h_out[idx] = f2bf(hv);
}

// ---------------------------------------------------------------------------
// persistent recurrence v11: LDS h-staging to kill read amplification.
// 128 wgs x 512 thr (8 waves). Group mb = bid&3 (32 wgs, XCDs {mb, mb+4}
// under round-robin). Per step each wg stages its group's 32KB h-slice into
// LDS ONCE (512 thr x 4 coherent dwordx4, XOR-swizzled rows), then all 8
// waves read fragments from LDS. Coherent read traffic: 4MB/step (was 16).
// R12 flag protocol + counted-vmcnt ledger: [out1, x16] + stage4 ->
// vmcnt(4) proves x, vmcnt(0) proves stage; x-prefetch flies across poll.
// ---------------------------------------------------------------------------
__global__ __launch_bounds__(512, 2) void qlstm_persistent(
    const u16* __restrict__ Xbf,    // [256][128][512] bf16
    u16* __restrict__ hbuf,         // [2][128][512] bf16
    const u16* __restrict__ Wt,     // [2048][1024] bf16, n = j*4+g
    const float* __restrict__ bpn,  // [2048] f32
    float* __restrict__ out,        // [256][128][512] + hx + cx
    u32* __restrict__ flags)        // [128]
{
  __shared__ __align__(16) u16 hs[16384];      // 32 rows x 512 (swizzled)
  __shared__ float pre_s[32][68];
  const int bid = blockIdx.x;
  const int mb = bid & 3, nb = bid >> 2;       // nb 0..31
  const int b0 = mb * 32;
  const int tid = threadIdx.x;                 // 0..511
  const int wv = tid >> 6, lane = tid & 63;
  const int rt = wv >> 2;                      // 0..1 row-tile
  const int ct = wv & 3;                       // 0..3 col-tile
  const int l15 = lane & 15, kg = lane >> 4;
  const int brow = b0 + rt * 16 + l15;         // global x/h row
  const int rloc = rt * 16 + l15;              // local row 0..31
  const int ncol = nb * 64 + ct * 16 + l15;    // gate col

  // W fragments (both halves), register-resident: 128 VGPR
  const u16* wrow = Wt + (size_t)ncol * 1024;
  bf16x8 warr[32];
#pragma unroll
  for (int kk = 0; kk < 32; ++kk)
    warr[kk] = *(const bf16x8*)(wrow + kk * 32 + kg * 8);
  const float bnc = bpn[ncol];

  // cell mapping: thread -> (crow 0..31, jl 0..15); hcol = nb*16 + jl
  const int crow = tid >> 4, jl = tid & 15;
  const size_t eidx = (size_t)(b0 + crow) * 512 + (size_t)(nb * 16 + jl);
  float cst = 0.f, hl = 0.f;

  // x prologue for t=0 (untracked; ledger)
  bf16x8 xf[16];
  {
    const u16* xr = Xbf + (size_t)brow * 512;
#pragma unroll
    for (int kk = 0; kk < 16; ++kk)
      ld_g_b128(xr + kk * 32 + kg * 8, xf[kk]);
  }

  for (int t = 0; t < 256; ++t) {
    // ---- poll group flags (wave 0, lanes<32); others sail to barrier ----
    if (t > 0 && tid < 32) {
      int guard = 0;
      while (__hip_atomic_load(&flags[mb + 4 * tid], __ATOMIC_RELAXED,
                               __HIP_MEMORY_SCOPE_AGENT) < (u32)t) {
        __builtin_amdgcn_s_sleep(1);
        if (++guard > 30000) break;            // bounded: fail loudly, no hang
      }
    }
    __builtin_amdgcn_s_barrier();              // A
    asm volatile("" ::: "memory");

    // ---- issue 4 coherent stage-loads of the 32KB h-slice ----
    bf16x8 sv[4];
    {
      const u16* hg = hbuf + (size_t)((t & 1) ? 65536 : 0) + (size_t)b0 * 512;
#pragma unroll
      for (int r = 0; r < 4; ++r)
        ld_llc_b128(hg + ((size_t)(r * 512 + tid) * 16) / 2, sv[r]);
    }

    // ---- x-MFMAs: vmcnt(4) proves [out1, x16] landed (4 stage in flight) ----
    asm volatile("s_waitcnt vmcnt(4)" ::: "memory");
    __builtin_amdgcn_sched_barrier(0);
    f32x4 ax0 = {0,0,0,0}, ax1 = {0,0,0,0};
#pragma unroll
    for (int kk = 0; kk < 16; kk += 2) {
      ax0 = __builtin_amdgcn_mfma_f32_16x16x32_bf16(xf[kk],     warr[kk],     ax0, 0, 0, 0);
      ax1 = __builtin_amdgcn_mfma_f32_16x16x32_bf16(xf[kk + 1], warr[kk + 1], ax1, 0, 0, 0);
    }

    // ---- stage -> LDS (XOR-swizzled rows), then barrier B ----
    asm volatile("s_waitcnt vmcnt(0)" ::: "memory");
    __builtin_amdgcn_sched_barrier(0);
#pragma unroll
    for (int r = 0; r < 4; ++r) {
      int o = (r * 512 + tid) * 16;            // byte offset in slice
      int row = o >> 10, cb = o & 1023;
      *(bf16x8*)((char*)hs + row * 1024 + (cb ^ ((row & 7) << 4))) = sv[r];
    }
    asm volatile("s_waitcnt lgkmcnt(0)" ::: "memory");
    __builtin_amdgcn_sched_barrier(0);
    __builtin_amdgcn_s_barrier();              // B: h staged
    asm volatile("" ::: "memory");

    // ---- h-MFMAs from LDS (unconditional; h=0 at t=0) ----
    f32x4 ah0 = {0,0,0,0}, ah1 = {0,0,0,0};
#pragma unroll
    for (int kk = 0; kk < 16; kk += 2) {
      int cb0 = (kk * 32 + kg * 8) * 2;
      int cb1 = ((kk + 1) * 32 + kg * 8) * 2;
      bf16x8 h0 = *(const bf16x8*)((const char*)hs + rloc * 1024 +
                                   (cb0 ^ ((rloc & 7) << 4)));
      bf16x8 h1 = *(const bf16x8*)((const char*)hs + rloc * 1024 +
                                   (cb1 ^ ((rloc & 7) << 4)));
      ah0 = __builtin_amdgcn_mfma_f32_16x16x32_bf16(h0, warr[16 + kk],     ah0, 0, 0, 0);
      ah1 = __builtin_amdgcn_mfma_f32_16x16x32_bf16(h1, warr[16 + kk + 1], ah1, 0, 0, 0);
    }
    f32x4 acc = (ax0 + ax1) + (ah0 + ah1);

    // ---- gate exchange via pre_s; barrier C ----
    // C/D layout: col = lane&15, row = (lane>>4)*4 + q
#pragma unroll
    for (int q = 0; q < 4; ++q)
      pre_s[rt * 16 + kg * 4 + q][ct * 16 + l15] = acc[q] + bnc;
    asm volatile("s_waitcnt lgkmcnt(0)" ::: "memory");
    __builtin_amdgcn_sched_barrier(0);
    __builtin_amdgcn_s_barrier();              // C
    asm volatile("" ::: "memory");

    // ---- gates + cell update (thread owns row=crow, hcol=nb*16+jl) ----
    float pf = pre_s[crow][jl * 4 + 0];
    float pi = pre_s[crow][jl * 4 + 1];
    float pu = pre_s[crow][jl * 4 + 2];
    float po = pre_s[crow][jl * 4 + 3];
    cst = sigm_fast(pf) * cst + sigm_fast(pi) * tanh_fast(pu);
    float hv = sigm_fast(po) * tanh_fast(cst);
    hl = hv;

    // ---- packed coherent h-store: 4 cols -> one dwordx2 (tid&3==0) ----
    u16 myh = f2bf(hv);
    u32 w  = (u32)myh | ((u32)(u16)__shfl_xor((int)(u32)myh, 1) << 16);
    u32 w2 = (u32)__shfl_xor((int)w, 2);
    u16* hnext = hbuf + (size_t)(((t + 1) & 1) ? 65536 : 0);
    if ((tid & 3) == 0) {
      u32x2 hw = {w, w2};
      st_llc_b64(hnext + (size_t)(b0 + crow) * 512 + (size_t)(nb * 16 + jl), hw);
    }
    asm volatile("s_waitcnt vmcnt(0)" ::: "memory");   // h-stores drained
    __builtin_amdgcn_s_barrier();              // D
    asm volatile("" ::: "memory");
    if (tid == 0)
      __hip_atomic_store(&flags[bid], (u32)(t + 1), __ATOMIC_RELAXED,
                         __HIP_MEMORY_SCOPE_AGENT);

    // ---- post-flag: out-store(1) then x-loads(16) — fly across next poll ----
    union { float f; u32 u; } ho; ho.f = hv;
    st_g_b32((u32*)(out + (size_t)t * 65536 + eidx), ho.u);
    if (t < 255) {
      const u16* xr = Xbf + (size_t)(t + 1) * 65536 + (size_t)brow * 512;
#pragma unroll
      for (int kk = 0; kk < 16; ++kk)
        ld_g_b128(xr + kk * 32 + kg * 8, xf[kk]);
    }
  }

  asm volatile("s_waitcnt vmcnt(0)" ::: "memory");
  out[(size_t)256 * 65536 + eidx] = hl;
  out[(size_t)256 * 65536 + 65536 + eidx] = cst;
}

// ---------------------------------------------------------------------------
extern "C" void kernel_launch(void* const* d_in, const int* in_sizes, int n_in,
                              void* d_out, int out_size, void* d_ws, size_t ws_size,
                              hipStream_t stream) {
  (void)in_sizes; (void)n_in; (void)out_size; (void)ws_size;
  const float* inp = (const float*)d_in[0];
  float* out = (float*)d_out;

  // ws: Xbf 33554432 | Wt 4194304 | bpn 8192 | hbuf 262144 | flags 1024 | cbuf 262144
  char* base = (char*)d_ws;
  u16*   Xbf   = (u16*)base;
  u16*   Wt    = (u16*)(base + 33554432);
  float* bpn   = (float*)(base + 33554432 + 4194304);
  u16*   hbuf  = (u16*)(base + 33554432 + 4194304 + 8192);
  u32*   flags = (u32*)(base + 33554432 + 4194304 + 8192 + 262144);
  float* cbuf  = (float*)(base + 33554432 + 4194304 + 8192 + 262144 + 1024);

  const float* W[4];  const float* b[4];  const float* rx[4];  const float* P[4];
  for (int g = 0; g < 4; ++g) {
    W[g]  = (const float*)d_in[1 + 4 * g];
    b[g]  = (const float*)d_in[2 + 4 * g];
    rx[g] = (const float*)d_in[3 + 4 * g];
    P[g]  = (const float*)d_in[4 + 4 * g];
  }
  fold_kernel<<<dim3(16, 8, 4), 256, 0, stream>>>(
      W[0], rx[0], P[0], W[1], rx[1], P[1],
      W[2], rx[2], P[2], W[3], rx[3], P[3], Wt);
  fold_bias<<<dim3(32), 256, 0, stream>>>(
      b[0], rx[0], P[0], b[1], rx[1], P[1],
      b[2], rx[2], P[2], b[3], rx[3], P[3], bpn);
  xcvt_kernel<<<16384, 256, 0, stream>>>(inp, Xbf);
  init_kernel<<<256, 256, 0, stream>>>((u32*)hbuf, cbuf, flags);

  void* args[6];
  const u16* Xbf_c = Xbf;
  const u16* Wt_c = Wt;
  const float* bpn_c = bpn;
  u16* hbuf_p = hbuf;
  float* out_p = out;
  u32* flags_p = flags;
  args[0] = (void*)&Xbf_c;
  args[1] = (void*)&hbuf_p;
  args[2] = (void*)&Wt_c;
  args[3] = (void*)&bpn_c;
  args[4] = (void*)&out_p;
  args[5] = (void*)&flags_p;
  hipError_t e = hipLaunchCooperativeKernel((const void*)qlstm_persistent,
                                            dim3(128), dim3(512), args, 0, stream);
  if (e != hipSuccess) {
    for (int t = 0; t < 256; ++t) {
      const u16* xb_t  = Xbf + (size_t)t * 65536;
      const u16* h_in  = hbuf + (size_t)(t & 1) * 65536;
      u16*       h_oup = hbuf + (size_t)((t & 1) ^ 1) * 65536;
      float*     out_t = out + (size_t)t * 65536;
      step_kernel<<<256, 256, 0, stream>>>(xb_t, h_in, h_oup, Wt, bpn, cbuf, out_t);
    }
    tail_kernel<<<256, 256, 0, stream>>>(out + (size_t)255 * 65536, cbuf,
                                         out + (size_t)256 * 65536,
                                         out + (size_t)256 * 65536 + 65536);
  }
}

// Round 18
// 1394.911 us; speedup vs baseline: 1.9932x; 1.1695x over previous
//
#include <hip/hip_runtime.h>
#include <hip/hip_bf16.h>

typedef __attribute__((ext_vector_type(8))) short bf16x8;
typedef __attribute__((ext_vector_type(4))) float f32x4;
typedef unsigned short u16;
typedef unsigned int u32;

__device__ __forceinline__ u16 f2bf(float f) {
  union { float f; unsigned u; } v; v.f = f;
  unsigned r = v.u + 0x7FFFu + ((v.u >> 16) & 1u);   // RTNE
  return (u16)(r >> 16);
}

__device__ __forceinline__ float sigm_fast(float x) {
  return __builtin_amdgcn_rcpf(1.f + __expf(-x));
}
__device__ __forceinline__ float tanh_fast(float x) {
  x = fminf(fmaxf(x, -15.f), 15.f);
  float e = __expf(2.f * x);
  return (e - 1.f) * __builtin_amdgcn_rcpf(e + 1.f);
}

// ---- untracked (inline-asm) memory ops: caller owns the vmcnt ledger ----
__device__ __forceinline__ void ld_llc_b128(const u16* p, bf16x8& r) {  // coherent
  asm volatile("global_load_dwordx4 %0, %1, off sc0 sc1" : "=&v"(r) : "v"(p));
}
__device__ __forceinline__ void ld_g_b128(const u16* p, bf16x8& r) {    // cached
  asm volatile("global_load_dwordx4 %0, %1, off" : "=&v"(r) : "v"(p));
}
__device__ __forceinline__ void st_llc_b32(u32* p, u32 v) {             // coherent
  asm volatile("global_store_dword %0, %1, off sc0 sc1" :: "v"(p), "v"(v) : "memory");
}
__device__ __forceinline__ void st_g_b32(u32* p, u32 v) {               // cached
  asm volatile("global_store_dword %0, %1, off" :: "v"(p), "v"(v) : "memory");
}

// ---------------------------------------------------------------------------
// fold (all 4 gates, z = gate): Wt[(j*4+g)][k] = sum_m P[m][j]*(W[k][m]*cos(rx[m]))
// ---------------------------------------------------------------------------
__global__ __launch_bounds__(256) void fold_kernel(
    const float* __restrict__ W0, const float* __restrict__ rx0, const float* __restrict__ P0,
    const float* __restrict__ W1, const float* __restrict__ rx1, const float* __restrict__ P1,
    const float* __restrict__ W2, const float* __restrict__ rx2, const float* __restrict__ P2,
    const float* __restrict__ W3, const float* __restrict__ rx3, const float* __restrict__ P3,
    u16* __restrict__ Wt)
{
  const int g = blockIdx.z;
  const float* W  = (g == 0) ? W0  : (g == 1) ? W1  : (g == 2) ? W2  : W3;
  const float* rx = (g == 0) ? rx0 : (g == 1) ? rx1 : (g == 2) ? rx2 : rx3;
  const float* P  = (g == 0) ? P0  : (g == 1) ? P1  : (g == 2) ? P2  : P3;
  __shared__ __align__(16) float As[16][68];
  __shared__ __align__(16) float Bs[16][68];
  const int bk = blockIdx.x, bj = blockIdx.y;
  const int tid = threadIdx.x;
  const int tx = tid & 15, ty = tid >> 4;
  const int j0 = bj * 64, k0 = bk * 64;
  float acc[4][4] = {};
  for (int m0 = 0; m0 < 512; m0 += 16) {
#pragma unroll
    for (int l = 0; l < 4; ++l) {
      int lin = tid + 256 * l;
      int mm = lin >> 6, jr = lin & 63;
      As[mm][jr] = P[(m0 + mm) * 512 + j0 + jr];
      int kk = lin >> 4, mb = lin & 15;
      Bs[mb][kk] = W[(k0 + kk) * 512 + m0 + mb] * cosf(rx[m0 + mb]);
    }
    __syncthreads();
#pragma unroll
    for (int mm = 0; mm < 16; ++mm) {
      f32x4 a = *(const f32x4*)&As[mm][ty * 4];
      f32x4 b = *(const f32x4*)&Bs[mm][tx * 4];
#pragma unroll
      for (int i = 0; i < 4; ++i)
#pragma unroll
        for (int jj = 0; jj < 4; ++jj)
          acc[i][jj] += a[i] * b[jj];
    }
    __syncthreads();
  }
#pragma unroll
  for (int i = 0; i < 4; ++i) {
    int j = j0 + ty * 4 + i;
    size_t n = (size_t)(j * 4 + g);
    ushort4 w;
    w.x = f2bf(acc[i][0]); w.y = f2bf(acc[i][1]);
    w.z = f2bf(acc[i][2]); w.w = f2bf(acc[i][3]);
    *(ushort4*)(Wt + n * 1024 + k0 + tx * 4) = w;
  }
}

// bpn[j*4+g]; grid 32 = 4 gates x 8 j-blocks
__global__ __launch_bounds__(256) void fold_bias(
    const float* __restrict__ b0, const float* __restrict__ rx0, const float* __restrict__ P0,
    const float* __restrict__ b1, const float* __restrict__ rx1, const float* __restrict__ P1,
    const float* __restrict__ b2, const float* __restrict__ rx2, const float* __restrict__ P2,
    const float* __restrict__ b3, const float* __restrict__ rx3, const float* __restrict__ P3,
    float* __restrict__ bpn)
{
  const int g = blockIdx.x >> 3, jb = blockIdx.x & 7;
  const float* b  = (g == 0) ? b0  : (g == 1) ? b1  : (g == 2) ? b2  : b3;
  const float* rx = (g == 0) ? rx0 : (g == 1) ? rx1 : (g == 2) ? rx2 : rx3;
  const float* P  = (g == 0) ? P0  : (g == 1) ? P1  : (g == 2) ? P2  : P3;
  __shared__ float bc[512];
  __shared__ float red[4][65];
  const int tid = threadIdx.x;
  bc[tid] = b[tid] * cosf(rx[tid]);
  bc[tid + 256] = b[tid + 256] * cosf(rx[tid + 256]);
  __syncthreads();
  const int jl = tid & 63, msub = tid >> 6;
  const int j = jb * 64 + jl;
  float acc = 0.f;
  for (int m = msub * 128; m < msub * 128 + 128; ++m)
    acc += bc[m] * P[m * 512 + j];
  red[msub][jl] = acc;
  __syncthreads();
  if (msub == 0)
    bpn[j * 4 + g] = red[0][jl] + red[1][jl] + red[2][jl] + red[3][jl];
}

__global__ __launch_bounds__(256) void xcvt_kernel(
    const float* __restrict__ x, u16* __restrict__ xb)
{
  size_t i = (size_t)blockIdx.x * 256 + threadIdx.x;
  f32x4 v = *(const f32x4*)(x + i * 4);
  ushort4 w;
  w.x = f2bf(v[0]); w.y = f2bf(v[1]); w.z = f2bf(v[2]); w.w = f2bf(v[3]);
  *(ushort4*)(xb + i * 4) = w;
}

// zero hbuf (both parities) + cbuf + flags, every launch (replay determinism)
__global__ __launch_bounds__(256) void init_kernel(unsigned* hbuf32, float* cbuf,
                                                   unsigned* flags) {
  int i = blockIdx.x * 256 + threadIdx.x;      // 65536
  hbuf32[i] = 0;
  cbuf[i] = 0.f;
  if (i < 256) flags[i] = 0;
}

__global__ __launch_bounds__(256) void tail_kernel(
    const float* __restrict__ hlast, const float* __restrict__ c,
    float* __restrict__ hx, float* __restrict__ cx)
{
  int i = blockIdx.x * 256 + threadIdx.x;
  hx[i] = hlast[i];
  cx[i] = c[i];
}

// ---------------------------------------------------------------------------
// fallback single-step kernel (R1-proven)
// ---------------------------------------------------------------------------
__global__ __launch_bounds__(256) void step_kernel(
    const u16* __restrict__ xb_t, const u16* __restrict__ h_in,
    u16* __restrict__ h_out, const u16* __restrict__ Wt,
    const float* __restrict__ bpn, float* __restrict__ cbuf,
    float* __restrict__ out_t)
{
  __shared__ float pre_s[32][33];
  const int bid = blockIdx.x;
  const int mb = bid >> 6, nb = bid & 63;
  const int b0 = mb * 32, n0 = nb * 32;
  const int tid = threadIdx.x;
  const int wv = tid >> 6, lane = tid & 63;
  const int rt = wv >> 1, nt = wv & 1;
  const int l15 = lane & 15, kg = lane >> 4;
  const int brow = b0 + rt * 16 + l15;
  const int ncol = n0 + nt * 16 + l15;
  const u16* wrow = Wt + (size_t)ncol * 1024;
  const u16* xrow = xb_t + (size_t)brow * 512;
  const u16* hrow = h_in + (size_t)brow * 512;
  f32x4 acc = {0.f, 0.f, 0.f, 0.f};
#pragma unroll 8
  for (int kk = 0; kk < 32; ++kk) {
    const int kb = kk * 32 + kg * 8;
    bf16x8 bfrag = *(const bf16x8*)(wrow + kb);
    bf16x8 afrag;
    if (kb < 512) afrag = *(const bf16x8*)(xrow + kb);
    else          afrag = *(const bf16x8*)(hrow + (kb - 512));
    acc = __builtin_amdgcn_mfma_f32_16x16x32_bf16(afrag, bfrag, acc, 0, 0, 0);
  }
  const float bias = bpn[ncol];
#pragma unroll
  for (int q = 0; q < 4; ++q)
    pre_s[rt * 16 + kg * 4 + q][nt * 16 + l15] = acc[q] + bias;
  __syncthreads();
  const int bb = tid >> 3, jo = tid & 7;
  float pf = pre_s[bb][jo * 4 + 0];
  float pi = pre_s[bb][jo * 4 + 1];
  float pu = pre_s[bb][jo * 4 + 2];
  float po = pre_s[bb][jo * 4 + 3];
  float fg = 1.f / (1.f + __expf(-pf));
  float ig = 1.f / (1.f + __expf(-pi));
  float gg = tanhf(pu);
  float og = 1.f / (1.f + __expf(-po));
  size_t idx = (size_t)(b0 + bb) * 512 + (size_t)(nb * 8 + jo);
  float cv = fg * cbuf[idx] + ig * gg;
  cbuf[idx] = cv;
  float hv = og * tanhf(cv);
  out_t[idx] = hv;
  h_out[idx] = f2bf(hv);
}

// ---------------------------------------------------------------------------
// persistent recurrence v12 = R12 (best known: 1319us) + PROMPT flag release:
//   - flag store -> global_atomic_swap (atomic path hits the LLC atomic unit
//     immediately; plain sc0sc1 stores can linger in WC buffers lazily)
//   - poll busy-spins (no s_sleep) so detection lands within one poll RTT.
// Everything else byte-identical to R12's proven protocol/ledger.
// ---------------------------------------------------------------------------
__global__ __launch_bounds__(256, 1) void qlstm_persistent(
    const u16* __restrict__ Xbf,    // [256][128][512] bf16
    u16* __restrict__ hbuf,         // [2][128][512] bf16
    const u16* __restrict__ Wt,     // [2048][1024] bf16, n = j*4+g
    const float* __restrict__ bpn,  // [2048] f32
    float* __restrict__ out,        // [256][128][512] + hx + cx
    unsigned* __restrict__ flags)   // [256]
{
  __shared__ float pre_s[32][33];
  const int bid = blockIdx.x;
  const int mb = bid >> 6, nb = bid & 63;
  const int b0 = mb * 32, n0 = nb * 32;
  const int tid = threadIdx.x;
  const int wv = tid >> 6, lane = tid & 63;
  const int rt = wv >> 1, nt = wv & 1;
  const int l15 = lane & 15, kg = lane >> 4;
  const int brow = b0 + rt * 16 + l15;
  const int ncol = n0 + nt * 16 + l15;

  // both W halves register-resident (128 VGPR)
  const u16* wrow = Wt + (size_t)ncol * 1024;
  bf16x8 warr[32];
#pragma unroll
  for (int kk = 0; kk < 32; ++kk)
    warr[kk] = *(const bf16x8*)(wrow + kk * 32 + kg * 8);
  const float bnc = bpn[ncol];

  const int bb = tid >> 3, jo = tid & 7;
  const size_t eidx = (size_t)(b0 + bb) * 512 + (size_t)(nb * 8 + jo);
  float cst = 0.f, hl = 0.f;

  // prologue: x-loads for t=0, drained once
  bf16x8 xf[16];
  {
    const u16* xr = Xbf + (size_t)brow * 512;
#pragma unroll
    for (int kk = 0; kk < 16; ++kk)
      ld_g_b128(xr + kk * 32 + kg * 8, xf[kk]);
    asm volatile("s_waitcnt vmcnt(0)" ::: "memory");
  }

  for (int t = 0; t < 256; ++t) {
    // ---- poll (wave 0, one flag per lane, BUSY SPIN); others to barrier ----
    if (t > 0 && tid < 64) {
      int guard = 0;
      while (__hip_atomic_load(&flags[mb * 64 + tid], __ATOMIC_RELAXED,
                               __HIP_MEMORY_SCOPE_AGENT) < (unsigned)t) {
        if (++guard > 2000000) break;        // bounded: fail loudly, no hang
      }
    }
    __builtin_amdgcn_s_barrier();            // A (no auto-drain)
    asm volatile("" ::: "memory");

    // ---- issue coherent h-loads (fly during x-MFMAs) ----
    bf16x8 hf[16];
    if (t > 0) {
      const u16* hr = hbuf + (size_t)((t & 1) ? 65536 : 0) + (size_t)brow * 512;
#pragma unroll
      for (int kk = 0; kk < 16; ++kk)
        ld_llc_b128(hr + kk * 32 + kg * 8, hf[kk]);
    }

    // ---- x-MFMAs: vmcnt(16) proves the 16 old x-loads landed ----
    asm volatile("s_waitcnt vmcnt(16)" ::: "memory");
    __builtin_amdgcn_sched_barrier(0);
    f32x4 ax0 = {0,0,0,0}, ax1 = {0,0,0,0};
#pragma unroll
    for (int kk = 0; kk < 16; kk += 2) {
      ax0 = __builtin_amdgcn_mfma_f32_16x16x32_bf16(xf[kk],     warr[kk],     ax0, 0, 0, 0);
      ax1 = __builtin_amdgcn_mfma_f32_16x16x32_bf16(xf[kk + 1], warr[kk + 1], ax1, 0, 0, 0);
    }

    // ---- h-MFMAs after vmcnt(0) ----
    f32x4 ah0 = {0,0,0,0}, ah1 = {0,0,0,0};
    if (t > 0) {
      asm volatile("s_waitcnt vmcnt(0)" ::: "memory");
      __builtin_amdgcn_sched_barrier(0);
#pragma unroll
      for (int kk = 0; kk < 16; kk += 2) {
        ah0 = __builtin_amdgcn_mfma_f32_16x16x32_bf16(hf[kk],     warr[16 + kk],     ah0, 0, 0, 0);
        ah1 = __builtin_amdgcn_mfma_f32_16x16x32_bf16(hf[kk + 1], warr[16 + kk + 1], ah1, 0, 0, 0);
      }
    }
    f32x4 acc = (ax0 + ax1) + (ah0 + ah1);

    // ---- LDS gate exchange; C/D: col=lane&15, row=(lane>>4)*4+q ----
#pragma unroll
    for (int q = 0; q < 4; ++q)
      pre_s[rt * 16 + kg * 4 + q][nt * 16 + l15] = acc[q] + bnc;
    asm volatile("s_waitcnt lgkmcnt(0)" ::: "memory");
    __builtin_amdgcn_sched_barrier(0);
    __builtin_amdgcn_s_barrier();            // B
    asm volatile("" ::: "memory");

    // ---- gates + cell update ----
    float pf = pre_s[bb][jo * 4 + 0];
    float pi = pre_s[bb][jo * 4 + 1];
    float pu = pre_s[bb][jo * 4 + 2];
    float po = pre_s[bb][jo * 4 + 3];
    cst = sigm_fast(pf) * cst + sigm_fast(pi) * tanh_fast(pu);
    float hv = sigm_fast(po) * tanh_fast(cst);
    hl = hv;

    // ---- coherent h-store (packed dwords); drain forces WC flush ----
    u16 myh = f2bf(hv);
    u32 partner = (u32)(u16)__shfl_xor((int)(u32)myh, 1);
    u16* hnext = hbuf + (size_t)(((t + 1) & 1) ? 65536 : 0);
    if ((tid & 1) == 0)
      st_llc_b32((u32*)(hnext + eidx), (u32)myh | (partner << 16));
    asm volatile("s_waitcnt vmcnt(0)" ::: "memory");
    __builtin_amdgcn_s_barrier();            // C
    asm volatile("" ::: "memory");
    if (tid == 0)
      (void)__hip_atomic_exchange(&flags[bid], (unsigned)(t + 1),
                                  __ATOMIC_RELAXED, __HIP_MEMORY_SCOPE_AGENT);

    // ---- post-flag: out-store(1) then x-loads(16) — stay in flight ----
    union { float f; u32 u; } ho; ho.f = hv;
    st_g_b32((u32*)(out + (size_t)t * 65536 + eidx), ho.u);
    if (t < 255) {
      const u16* xr = Xbf + (size_t)(t + 1) * 65536 + (size_t)brow * 512;
#pragma unroll
      for (int kk = 0; kk < 16; ++kk)
        ld_g_b128(xr + kk * 32 + kg * 8, xf[kk]);
    }
  }

  asm volatile("s_waitcnt vmcnt(0)" ::: "memory");
  out[(size_t)256 * 65536 + eidx] = hl;
  out[(size_t)256 * 65536 + 65536 + eidx] = cst;
}

// ---------------------------------------------------------------------------
extern "C" void kernel_launch(void* const* d_in, const int* in_sizes, int n_in,
                              void* d_out, int out_size, void* d_ws, size_t ws_size,
                              hipStream_t stream) {
  (void)in_sizes; (void)n_in; (void)out_size; (void)ws_size;
  const float* inp = (const float*)d_in[0];
  float* out = (float*)d_out;

  char* base = (char*)d_ws;
  u16*      Xbf   = (u16*)base;
  u16*      Wt    = (u16*)(base + 33554432);
  float*    bpn   = (float*)(base + 33554432 + 4194304);
  u16*      hbuf  = (u16*)(base + 33554432 + 4194304 + 8192);
  unsigned* flags = (unsigned*)(base + 33554432 + 4194304 + 8192 + 262144);
  float*    cbuf  = (float*)(base + 33554432 + 4194304 + 8192 + 262144 + 1024);

  const float* W[4];  const float* b[4];  const float* rx[4];  const float* P[4];
  for (int g = 0; g < 4; ++g) {
    W[g]  = (const float*)d_in[1 + 4 * g];
    b[g]  = (const float*)d_in[2 + 4 * g];
    rx[g] = (const float*)d_in[3 + 4 * g];
    P[g]  = (const float*)d_in[4 + 4 * g];
  }
  fold_kernel<<<dim3(16, 8, 4), 256, 0, stream>>>(
      W[0], rx[0], P[0], W[1], rx[1], P[1],
      W[2], rx[2], P[2], W[3], rx[3], P[3], Wt);
  fold_bias<<<dim3(32), 256, 0, stream>>>(
      b[0], rx[0], P[0], b[1], rx[1], P[1],
      b[2], rx[2], P[2], b[3], rx[3], P[3], bpn);
  xcvt_kernel<<<16384, 256, 0, stream>>>(inp, Xbf);
  init_kernel<<<256, 256, 0, stream>>>((unsigned*)hbuf, cbuf, flags);

  void* args[6];
  const u16* Xbf_c = Xbf;
  const u16* Wt_c = Wt;
  const float* bpn_c = bpn;
  u16* hbuf_p = hbuf;
  float* out_p = out;
  unsigned* flags_p = flags;
  args[0] = (void*)&Xbf_c;
  args[1] = (void*)&hbuf_p;
  args[2] = (void*)&Wt_c;
  args[3] = (void*)&bpn_c;
  args[4] = (void*)&out_p;
  args[5] = (void*)&flags_p;
  hipError_t e = hipLaunchCooperativeKernel((const void*)qlstm_persistent,
                                            dim3(256), dim3(256), args, 0, stream);
  if (e != hipSuccess) {
    for (int t = 0; t < 256; ++t) {
      const u16* xb_t  = Xbf + (size_t)t * 65536;
      const u16* h_in  = hbuf + (size_t)(t & 1) * 65536;
      u16*       h_oup = hbuf + (size_t)((t & 1) ^ 1) * 65536;
      float*     out_t = out + (size_t)t * 65536;
      step_kernel<<<256, 256, 0, stream>>>(xb_t, h_in, h_oup, Wt, bpn, cbuf, out_t);
    }
    tail_kernel<<<256, 256, 0, stream>>>(out + (size_t)255 * 65536, cbuf,
                                         out + (size_t)256 * 65536,
                                         out + (size_t)256 * 65536 + 65536);
  }
}